// Round 1
// baseline (827.905 us; speedup 1.0000x reference)
//
#include <hip/hip_runtime.h>

// y = (x + 2) + (x * 3) - (x - 1) * (x / 2), elementwise fp32.
// Pure streaming: 0.54 GB read + 0.54 GB write -> ~170 us floor at 6.3 TB/s.
// Probe: grid-stride 2048 blocks (8/CU) + nontemporal ld/st to pin the kernel
// at the streaming floor; timed region is otherwise dominated by harness
// poison fills (~340 us each at 6.3 TB/s, see rocprof fillBufferAligned rows).

typedef float v4f __attribute__((ext_vector_type(4)));

__device__ __forceinline__ float fuse1(float x) {
    // Keep the reference's operation order for bit-compatible rounding.
    return (x + 2.0f) + (x * 3.0f) - (x - 1.0f) * (x * 0.5f);
}

__global__ __launch_bounds__(256) void fused_elemwise_kernel(
    const float* __restrict__ x, float* __restrict__ out, long long n4) {
    const v4f* __restrict__ x4 = (const v4f*)x;
    v4f* __restrict__ o4 = (v4f*)out;
    const long long stride = (long long)gridDim.x * blockDim.x;
    for (long long i = (long long)blockIdx.x * blockDim.x + threadIdx.x;
         i < n4; i += stride) {
        v4f v = __builtin_nontemporal_load(x4 + i);
        v4f r;
        r[0] = fuse1(v[0]);
        r[1] = fuse1(v[1]);
        r[2] = fuse1(v[2]);
        r[3] = fuse1(v[3]);
        __builtin_nontemporal_store(r, o4 + i);
    }
}

extern "C" void kernel_launch(void* const* d_in, const int* in_sizes, int n_in,
                              void* d_out, int out_size, void* d_ws, size_t ws_size,
                              hipStream_t stream) {
    const float* x = (const float*)d_in[0];
    float* out = (float*)d_out;
    long long n = (long long)in_sizes[0];  // 134217728, divisible by 4
    long long n4 = n / 4;                  // 33554432 float4s
    int block = 256;
    // 2048 blocks = 8 per CU; each thread runs exactly 64 grid-stride iters.
    int grid = 2048;
    fused_elemwise_kernel<<<grid, block, 0, stream>>>(x, out, n4);
}

// Round 2
// 812.304 us; speedup vs baseline: 1.0192x; 1.0192x over previous
//
#include <hip/hip_runtime.h>

// y = (x + 2) + (x * 3) - (x - 1) * (x / 2), elementwise fp32.
// Streaming kernel; timed region is dominated by 2x ~340us harness poison
// fills (2.147 GB each at ~6.3 TB/s) we cannot touch. Kernel's own share is
// ~126 us — BELOW the 170 us pure-HBM floor, i.e. it already rides L3 hits
// on the input across graph-replay iterations (input 537 MB vs L3 256 MB,
// partial residency). Round-1 lesson: nt LOADS kill that reuse (-22 us
// regression). This version: regular loads (L3 hits allowed) + nontemporal
// STORES only (output is never re-read; don't let the 537 MB output stream
// evict input lines from L3). One-shot grid as in the 806 us round-0 best.

typedef float v4f __attribute__((ext_vector_type(4)));

__device__ __forceinline__ float fuse1(float x) {
    // Keep the reference's operation order for bit-compatible rounding.
    return (x + 2.0f) + (x * 3.0f) - (x - 1.0f) * (x * 0.5f);
}

__global__ __launch_bounds__(256) void fused_elemwise_kernel(
    const float* __restrict__ x, float* __restrict__ out, long long n4) {
    long long i = (long long)blockIdx.x * blockDim.x + threadIdx.x;
    if (i >= n4) return;
    const v4f* __restrict__ x4 = (const v4f*)x;
    v4f* __restrict__ o4 = (v4f*)out;
    v4f v = x4[i];                      // regular load: allow L2/L3 hits
    v4f r;
    r[0] = fuse1(v[0]);
    r[1] = fuse1(v[1]);
    r[2] = fuse1(v[2]);
    r[3] = fuse1(v[3]);
    __builtin_nontemporal_store(r, o4 + i);  // output never re-read
}

extern "C" void kernel_launch(void* const* d_in, const int* in_sizes, int n_in,
                              void* d_out, int out_size, void* d_ws, size_t ws_size,
                              hipStream_t stream) {
    const float* x = (const float*)d_in[0];
    float* out = (float*)d_out;
    long long n = (long long)in_sizes[0];  // 134217728, divisible by 4
    long long n4 = n / 4;                  // 33554432 float4s
    int block = 256;
    long long grid = (n4 + block - 1) / block;  // 131072 blocks, one-shot
    fused_elemwise_kernel<<<(dim3)(unsigned)grid, block, 0, stream>>>(x, out, n4);
}

// Round 3
// 806.808 us; speedup vs baseline: 1.0261x; 1.0068x over previous
//
#include <hip/hip_runtime.h>

// y = (x + 2) + (x * 3) - (x - 1) * (x / 2), elementwise fp32.
// FINAL (revert to round-0 best, 806 us measured).
//
// Structural analysis of the timed region (rocprof, rounds 0-2):
//  - 2x __amd_rocclr_fillBufferAligned poison fills ~340 us each
//    (2.147 GB at 6.2-6.35 TB/s = achievable memset ceiling, 78-79% of
//    8 TB/s spec). Harness-owned; dominates dur_us (~680 of ~806 us).
//  - This kernel: ~126 us implied share for 1.07 GB traffic = 8.5 TB/s
//    effective, ABOVE the 6.3 TB/s HBM ceiling via partial L3 residency
//    of the input across graph replays.
// Experiments: nt load+store (-22 us, kills L3 reuse), nt store-only
// (-6 us, neutral/noise), capped grid-stride (neutral). Plain one-shot
// float4 is the measured best; no remaining pipe to win on
// (VALUBusy ~5%, no LDS, fully coalesced).

__device__ __forceinline__ float fuse1(float x) {
    // Keep the reference's operation order for bit-compatible rounding.
    return (x + 2.0f) + (x * 3.0f) - (x - 1.0f) * (x * 0.5f);
}

__global__ __launch_bounds__(256) void fused_elemwise_kernel(
    const float* __restrict__ x, float* __restrict__ out, long long n4) {
    long long i = (long long)blockIdx.x * blockDim.x + threadIdx.x;
    if (i >= n4) return;
    const float4* __restrict__ x4 = (const float4*)x;
    float4* __restrict__ o4 = (float4*)out;
    float4 v = x4[i];
    float4 r;
    r.x = fuse1(v.x);
    r.y = fuse1(v.y);
    r.z = fuse1(v.z);
    r.w = fuse1(v.w);
    o4[i] = r;
}

extern "C" void kernel_launch(void* const* d_in, const int* in_sizes, int n_in,
                              void* d_out, int out_size, void* d_ws, size_t ws_size,
                              hipStream_t stream) {
    const float* x = (const float*)d_in[0];
    float* out = (float*)d_out;
    long long n = (long long)in_sizes[0];      // 134217728, divisible by 4
    long long n4 = n / 4;                       // 33554432
    int block = 256;
    long long grid = (n4 + block - 1) / block;  // 131072 blocks
    fused_elemwise_kernel<<<(dim3)(unsigned)grid, block, 0, stream>>>(x, out, n4);
}